// Round 1
// 696.798 us; speedup vs baseline: 1.0730x; 1.0730x over previous
//
#include <hip/hip_runtime.h>
#include <float.h>
#include <math.h>

#define C    1024
#define NQ   10
#define G4   500       // fused-kernel grid: 500 * 200 = 100000 rows exactly
#define LGS  16        // lg/w LDS row stride (floats)
#define RSUB 25        // rows per sub-chunk (8 sub-chunks per block at rpb=200)

// ---- wave64 sum via DPP (pure VALU; avoids ds_swizzle LDS-pipe cost) ------
template <int CTRL, int ROWM>
__device__ __forceinline__ float dpp_add(float x) {
  int mv = __builtin_amdgcn_update_dpp(0, __float_as_int(x), CTRL, ROWM, 0xf, true);
  return x + __int_as_float(mv);
}
__device__ __forceinline__ float wave_sum64(float x) {
  x = dpp_add<0xB1,  0xf>(x);  // quad_perm [1,0,3,2]  (xor 1)
  x = dpp_add<0x4E,  0xf>(x);  // quad_perm [2,3,0,1]  (xor 2)
  x = dpp_add<0x141, 0xf>(x);  // row_half_mirror      (xor-pair 4)
  x = dpp_add<0x140, 0xf>(x);  // row_mirror           (xor-pair 8)
  x = dpp_add<0x142, 0xa>(x);  // row_bcast15 -> rows 1,3
  x = dpp_add<0x143, 0xc>(x);  // row_bcast31 -> rows 2,3
  return __int_as_float(__builtin_amdgcn_readlane(__float_as_int(x), 63));
}

// ---------------- K0: qd[k] = Qn[k] - Qn[NQ] -------------------------------
__global__ __launch_bounds__(256) void k0_qdiff(const float* __restrict__ Q,
                                                float* __restrict__ qd) {
  __shared__ float red[256];
  __shared__ float inorm[NQ + 1];
  int t = threadIdx.x;
  for (int k = 0; k <= NQ; ++k) {
    float s = 0.f;
    for (int c = t; c < C; c += 256) { float v = Q[k * C + c]; s = fmaf(v, v, s); }
    red[t] = s; __syncthreads();
    for (int st = 128; st > 0; st >>= 1) {
      if (t < st) red[t] += red[t + st];
      __syncthreads();
    }
    if (t == 0) inorm[k] = 1.0f / fmaxf(sqrtf(red[0]), 1e-12f);
    __syncthreads();
  }
  for (int k = 0; k < NQ; ++k)
    for (int c = t; c < C; c += 256)
      qd[k * C + c] = Q[k * C + c] * inorm[k] - Q[NQ * C + c] * inorm[NQ];
}

// ---------------- KF: fused logits + online-softmax accumulation -----------
// One block owns rpb contiguous rows, processed in RSUB-row sub-chunks.
// Phase A (wave-PAIR per row): waves (2p, 2p+1) both load row i (i%2==p);
//   wave's half = wv&1 computes 5 of the 10 query dots (q frags 80 VGPRs).
//   DPP-reduced logits -> LDS; per-wave running max -> LDS.
// Rescale: m_new = max(m_old, chunk max); a,ds *= exp(m_old-m_new).
// stage-W: w = exp(lg - m_new) computed ONCE per (row,k) in LDS (in place).
// Phase B (thread per 4 cols): re-read rows (L1/L2-hot, just touched by A),
//   a[k][j] += w*x, ds[k] += w.  X streams from HBM exactly once.
__global__ __launch_bounds__(256, 2) void kf_fused(const float* __restrict__ X,
                                                   const float* __restrict__ qd,
                                                   float* __restrict__ partial,
                                                   float* __restrict__ dsum,
                                                   float* __restrict__ mblk,
                                                   int N, int rpb) {
  __shared__ float lgbuf[2][RSUB][LGS];   // logits, overwritten by weights
  __shared__ float wmS[4][8];             // per-wave 5-query max
  __shared__ float sMnew[16];             // running max, for stage-W

  const int g = blockIdx.x, t = threadIdx.x;
  const int l = t & 63, wv = t >> 6;
  const int pr = wv >> 1;                 // pair id: rows i%2==pr
  const int qbase = (wv & 1) * 5;         // query group: 0..4 or 5..9
  const int co = l << 2;

  const int n0 = g * rpb;
  const int n1 = min(n0 + rpb, N);

  float4 q4[5][4];                        // 80 VGPRs of query fragments
#pragma unroll
  for (int k = 0; k < 5; ++k)
#pragma unroll
    for (int j = 0; j < 4; ++j)
      q4[k][j] = *(const float4*)(qd + (qbase + k) * C + j * 256 + co);

  float a[NQ][4], ds[NQ], mo[NQ];
#pragma unroll
  for (int k = 0; k < NQ; ++k) {
    a[k][0] = a[k][1] = a[k][2] = a[k][3] = 0.f;
    ds[k] = 0.f; mo[k] = -FLT_MAX;
  }

  int s = 0;
  for (int c0 = n0; c0 < n1; c0 += RSUB) {
    const int cnt = min(RSUB, n1 - c0);

    // ---- phase A: logits ----
    float wmx[5];
#pragma unroll
    for (int k = 0; k < 5; ++k) wmx[k] = -FLT_MAX;

    for (int i = pr; i < cnt; i += 2) {
      const float* xp = X + (size_t)(c0 + i) * C + co;
      float4 xv[4];
#pragma unroll
      for (int j = 0; j < 4; ++j) xv[j] = *(const float4*)(xp + j * 256);

      float ss = 0.f, dot[5];
#pragma unroll
      for (int k = 0; k < 5; ++k) dot[k] = 0.f;
#pragma unroll
      for (int j = 0; j < 4; ++j) {
        float4 v = xv[j];
        ss = fmaf(v.x, v.x, fmaf(v.y, v.y, fmaf(v.z, v.z, fmaf(v.w, v.w, ss))));
#pragma unroll
        for (int k = 0; k < 5; ++k) {
          float4 q = q4[k][j];
          dot[k] = fmaf(v.x, q.x, fmaf(v.y, q.y, fmaf(v.z, q.z, fmaf(v.w, q.w, dot[k]))));
        }
      }
      float ssu = wave_sum64(ss);
      float rn  = 100.0f / fmaxf(sqrtf(ssu), 1e-12f);
#pragma unroll
      for (int k = 0; k < 5; ++k) {
        float lg = wave_sum64(dot[k]) * rn;
        wmx[k] = fmaxf(wmx[k], lg);
        if (l == 0) lgbuf[s][i][qbase + k] = lg;
      }
    }
    if (l == 0) {
#pragma unroll
      for (int k = 0; k < 5; ++k) wmS[wv][k] = wmx[k];
    }
    __syncthreads();

    // ---- rescale (all threads compute identical m_new) ----
#pragma unroll
    for (int k = 0; k < NQ; ++k) {
      float cm = (k < 5) ? fmaxf(wmS[0][k], wmS[2][k])
                         : fmaxf(wmS[1][k - 5], wmS[3][k - 5]);
      float mn = fmaxf(mo[k], cm);
      float sc = __expf(mo[k] - mn);       // first chunk: exp(-inf)=0, a,ds==0
      ds[k] *= sc;
      a[k][0] *= sc; a[k][1] *= sc; a[k][2] *= sc; a[k][3] *= sc;
      mo[k] = mn;
      if (t == 0) sMnew[k] = mn;
    }
    __syncthreads();

    // ---- stage-W: one exp per (row,k), in place ----
    for (int idx = t; idx < cnt * LGS; idx += 256) {
      int rr = idx >> 4, k = idx & 15;
      if (k < NQ) lgbuf[s][rr][k] = __expf(lgbuf[s][rr][k] - sMnew[k]);
    }
    __syncthreads();

    // ---- phase B: accumulate (rows are cache-hot) ----
#pragma unroll 2
    for (int i = 0; i < cnt; ++i) {
      float4 x4 = *(const float4*)&X[(size_t)(c0 + i) * C + (t << 2)];
      float4 wA = *(const float4*)&lgbuf[s][i][0];
      float4 wB = *(const float4*)&lgbuf[s][i][4];
      float2 wC = *(const float2*)&lgbuf[s][i][8];
#define ACC(K, W)                                            \
      ds[K] += (W);                                          \
      a[K][0] = fmaf((W), x4.x, a[K][0]);                    \
      a[K][1] = fmaf((W), x4.y, a[K][1]);                    \
      a[K][2] = fmaf((W), x4.z, a[K][2]);                    \
      a[K][3] = fmaf((W), x4.w, a[K][3]);
      ACC(0, wA.x) ACC(1, wA.y) ACC(2, wA.z) ACC(3, wA.w)
      ACC(4, wB.x) ACC(5, wB.y) ACC(6, wB.z) ACC(7, wB.w)
      ACC(8, wC.x) ACC(9, wC.y)
#undef ACC
    }
    s ^= 1;
  }

  // ---- store per-block partials, denoms, maxima ----
#pragma unroll
  for (int k = 0; k < NQ; ++k) {
    float4 o; o.x = a[k][0]; o.y = a[k][1]; o.z = a[k][2]; o.w = a[k][3];
    *(float4*)&partial[(((size_t)(g * NQ + k)) << 10) + (t << 2)] = o;
  }
  if (t == 0) {
#pragma unroll
    for (int k = 0; k < NQ; ++k) {
      dsum[g * NQ + k] = ds[k];
      mblk[g * 16 + k] = mo[k];
    }
  }
}

// ---------------- K5a: combine partials with per-block max correction ------
// pooled[c] = sum_k [ sum_g exp(m_g-M_k) a_g[k][c] ] / (NQ * D_k),
//   D_k = sum_g exp(m_g-M_k) ds_g[k],  M_k = max_g m_g[k]
__global__ __launch_bounds__(256) void k5a_pooled(const float* __restrict__ partial,
                                                  const float* __restrict__ dsum,
                                                  const float* __restrict__ mblk,
                                                  float* __restrict__ pooled) {
  __shared__ float sM[16], sF[16];
  __shared__ float red[256];
  __shared__ float r4[256][4];
  int t = threadIdx.x;
  int k = t & 15, grp = t >> 4;

  float mm = -FLT_MAX;
  if (k < NQ)
    for (int g = grp; g < G4; g += 16) mm = fmaxf(mm, mblk[g * 16 + k]);
  red[t] = mm; __syncthreads();
  if (t < 16) {
    float m2 = red[t];
    for (int j = 1; j < 16; ++j) m2 = fmaxf(m2, red[t + 16 * j]);
    sM[t] = m2;
  }
  __syncthreads();

  float dd = 0.f;
  if (k < NQ) {
    float Mk = sM[k];
    for (int g = grp; g < G4; g += 16)
      dd += dsum[g * NQ + k] * __expf(mblk[g * 16 + k] - Mk);
  }
  red[t] = dd; __syncthreads();
  if (t < 16) {
    float d2 = 0.f;
    for (int j = 0; j < 16; ++j) d2 += red[t + 16 * j];
    sF[t] = 1.0f / ((float)NQ * d2);      // only t<NQ entries are consumed
  }
  __syncthreads();

  int c0 = blockIdx.x * 4;
  float a0 = 0.f, a1 = 0.f, a2 = 0.f, a3 = 0.f;
  for (int idx = t; idx < G4 * NQ; idx += 256) {
    int g = idx / NQ, kq = idx - g * NQ;
    float f = __expf(mblk[g * 16 + kq] - sM[kq]) * sF[kq];
    const float4 p = *(const float4*)&partial[(((size_t)idx) << 10) + c0];
    a0 = fmaf(p.x, f, a0); a1 = fmaf(p.y, f, a1);
    a2 = fmaf(p.z, f, a2); a3 = fmaf(p.w, f, a3);
  }
  r4[t][0] = a0; r4[t][1] = a1; r4[t][2] = a2; r4[t][3] = a3;
  __syncthreads();
  for (int st = 128; st > 0; st >>= 1) {
    if (t < st) {
      r4[t][0] += r4[t + st][0]; r4[t][1] += r4[t + st][1];
      r4[t][2] += r4[t + st][2]; r4[t][3] += r4[t + st][3];
    }
    __syncthreads();
  }
  if (t < 4) pooled[c0 + t] = r4[0][t];
}

// ---------------- K5b: out[j] = b[j] + sum_c pooled[c] * W[j][c] -----------
__global__ __launch_bounds__(256) void k5b_out(const float* __restrict__ W,
                                               const float* __restrict__ bias,
                                               const float* __restrict__ pooled,
                                               float* __restrict__ out) {
  __shared__ float sp[C];
  int t = threadIdx.x;
  for (int i = t; i < C; i += 256) sp[i] = pooled[i];
  __syncthreads();
  int wv = t >> 6, lane = t & 63;
#pragma unroll
  for (int jj = 0; jj < 8; ++jj) {
    int j = blockIdx.x * 32 + wv * 8 + jj;
    float s = 0.f;
#pragma unroll
    for (int seg = 0; seg < 4; ++seg) {
      int cbase = seg * 256 + lane * 4;
      float4 w4 = *(const float4*)&W[(size_t)j * C + cbase];
      float4 p4 = *(const float4*)&sp[cbase];
      s += w4.x * p4.x + w4.y * p4.y + w4.z * p4.z + w4.w * p4.w;
    }
#pragma unroll
    for (int off = 32; off > 0; off >>= 1) s += __shfl_down(s, off);
    if (lane == 0) out[j] = s + bias[j];
  }
}

// ---------------------------------------------------------------------------
extern "C" void kernel_launch(void* const* d_in, const int* in_sizes, int n_in,
                              void* d_out, int out_size, void* d_ws, size_t ws_size,
                              hipStream_t stream) {
  const float* X = (const float*)d_in[0];
  const float* Q = (const float*)d_in[1];
  const float* W = (const float*)d_in[2];
  const float* b = (const float*)d_in[3];
  float* out = (float*)d_out;

  int N   = in_sizes[0] / C;               // 100000
  int rpb = (N + G4 - 1) / G4;             // 200

  float* ws      = (float*)d_ws;
  float* qd      = ws;                               // NQ*C
  float* mblk    = qd + NQ * C;                      // G4*16
  float* dsum    = mblk + G4 * 16;                   // G4*NQ
  float* pooled  = dsum + G4 * NQ;                   // C
  float* partial = pooled + C;                       // G4*NQ*C (~21 MB)

  hipLaunchKernelGGL(k0_qdiff,  dim3(1),      dim3(256), 0, stream, Q, qd);
  hipLaunchKernelGGL(kf_fused,  dim3(G4),     dim3(256), 0, stream,
                     X, qd, partial, dsum, mblk, N, rpb);
  hipLaunchKernelGGL(k5a_pooled,dim3(C / 4),  dim3(256), 0, stream,
                     partial, dsum, mblk, pooled);
  hipLaunchKernelGGL(k5b_out,   dim3(C / 32), dim3(256), 0, stream, W, b, pooled, out);
}